// Round 12
// baseline (293.720 us; speedup 1.0000x reference)
//
#include <hip/hip_runtime.h>
#include <hip/hip_bf16.h>
#include <math.h>

// VectorQuantizer: z [8,256,32,32] f32, codebook [8192,256] f32
// outputs (flat f32): z_q [2097152] NCHW, idx [8192] (as float), loss, perplexity
#define KC 8192
#define DD 256
#define NP 8192
#define ZQ_ELEMS 2097152
#define MARGIN_S 2.5e-4f   // s-space (== 5e-4 in d-space, validated rounds 4-11)

// ws layout (bytes)
#define OFF_ABIG 0u           // bf16 [8192][512]  (Zh | Zl)  points
#define OFF_BBIG 8388608u     // bf16 [8192][512]  (Wh | Wl)  codes
#define OFF_NRM  16777216u    // f32 [8192]
#define OFF_WSQ  16809984u    // f32 [8192]
#define OFF_P    16842752u    // u64 [8192]  global best  (mono(s)<<32 | k)
#define OFF_P2   16908288u    // u64 [8192]  global second-best
#define OFF_R    16973824u    // u64 [8192]  exact rescore result (d-space)
#define OFF_LOSSP 17039360u   // f64 [512]
#define OFF_HIST 17043456u    // i32 [8192]
#define OFF_DONE 17076224u    // u32 [1]

typedef __attribute__((ext_vector_type(8))) short bf16x8;
typedef __attribute__((ext_vector_type(4))) float f32x4;
typedef __attribute__((address_space(3))) void as3_void;
typedef const __attribute__((address_space(1))) void as1_cvoid;

#define GLOAD16(g, l) __builtin_amdgcn_global_load_lds((as1_cvoid*)(g), (as3_void*)(l), 16, 0, 0)

__device__ inline double waveReduceD(double v) {
#pragma unroll
    for (int off = 32; off; off >>= 1) v += __shfl_down(v, off, 64);
    return v;
}

static __device__ inline unsigned short f2bf(float f) {
    __hip_bfloat16 h = __float2bfloat16(f);  // RNE
    return *(unsigned short*)&h;
}
static __device__ inline float bf2f(unsigned short u) {
    unsigned v = ((unsigned)u) << 16;
    float f;
    __builtin_memcpy(&f, &v, 4);
    return f;
}
static __device__ inline unsigned mono(float f) {
    unsigned b = __float_as_uint(f);
    return (b & 0x80000000u) ? ~b : (b | 0x80000000u);
}
static __device__ inline float invmono(unsigned u) {
    unsigned b = (u & 0x80000000u) ? (u & 0x7FFFFFFFu) : ~u;
    return __uint_as_float(b);
}

// fused prep:
//   blocks 0..2047: 4 codebook rows each (wave-per-row: normalize + split +
//                   wsq/nrm + P/P2/R sentinels); blocks 0..31 zero hist; 32: done
//   blocks 2048..2559: z tile-transpose (64d x 64hw, LDS-staged) + hi/lo split
__global__ __launch_bounds__(256) void prep(
    const float* __restrict__ cb, const float* __restrict__ z,
    unsigned short* __restrict__ Bbig, unsigned short* __restrict__ Abig,
    float* __restrict__ nrm, float* __restrict__ wsq, int* __restrict__ hist,
    unsigned long long* __restrict__ P, unsigned long long* __restrict__ P2,
    unsigned long long* __restrict__ R, unsigned int* __restrict__ done) {
    int bid = blockIdx.x, t = threadIdx.x;
    int lane = t & 63, wid = t >> 6;
    if (bid < 2048) {
        if (bid < 32) hist[bid * 256 + t] = 0;
        if (bid == 32 && t == 0) *done = 0u;
        int k = bid * 4 + wid;
        float4 c4 = *(const float4*)&cb[(size_t)k * DD + lane * 4];
        double s = (double)c4.x * c4.x + (double)c4.y * c4.y
                 + (double)c4.z * c4.z + (double)c4.w * c4.w;
#pragma unroll
        for (int off = 32; off; off >>= 1) s += __shfl_xor(s, off, 64);
        float mh = fmaxf(sqrtf((float)s), 1e-12f);
        if (lane == 0) {
            nrm[k] = mh;
            wsq[k] = (float)(s / ((double)mh * (double)mh));
            P[k] = 0xFFFFFFFFFFFFFFFFull;
            P2[k] = 0xFFFFFFFFFFFFFFFFull;
            R[k] = 0xFFFFFFFFFFFFFFFFull;
        }
        float wv[4] = {c4.x / mh, c4.y / mh, c4.z / mh, c4.w / mh};
        unsigned short hi[4], lo[4];
#pragma unroll
        for (int j = 0; j < 4; ++j) {
            hi[j] = f2bf(wv[j]);
            lo[j] = f2bf(wv[j] - bf2f(hi[j]));
        }
        *(ushort4*)&Bbig[(size_t)k * 512 + lane * 4] = make_ushort4(hi[0], hi[1], hi[2], hi[3]);
        *(ushort4*)&Bbig[(size_t)k * 512 + 256 + lane * 4] = make_ushort4(lo[0], lo[1], lo[2], lo[3]);
    } else {
        __shared__ float tile[64][65];
        int zb = bid - 2048;               // 0..511
        int b = zb >> 6, ht = (zb >> 2) & 15, dt = zb & 3;
        int hw0 = ht * 64, d0 = dt * 64;
#pragma unroll
        for (int i = 0; i < 16; ++i) {
            int dl = wid * 16 + i;
            tile[dl][lane] = z[(size_t)(b * DD + d0 + dl) * 1024 + hw0 + lane];
        }
        __syncthreads();
        // point row n = b*1024+hw0+nl needs z(d=d0+lane, hw=hw0+nl) == tile[lane][nl]
#pragma unroll
        for (int i = 0; i < 16; ++i) {
            int nl = wid * 16 + i;
            float v = tile[lane][nl];
            unsigned short hi = f2bf(v);
            unsigned short lo = f2bf(v - bf2f(hi));
            size_t base = (size_t)(b * 1024 + hw0 + nl) * 512 + d0 + lane;
            Abig[base] = hi;
            Abig[base + 256] = lo;
        }
    }
}

// Deep-pipelined MFMA GEMM + atomic global top-2 epilogue.
// K-loop identical to verified R11 (quad-buffer, depth-3, vmcnt(8), reg pipeline).
// Epilogue: lock-free exact top-2 — old=atomicMin(P,x); atomicMin(P2,max(old,x));
// atomicMin(P2, v2_block). P2 provably ends as the exact global second-best.
__global__ __launch_bounds__(512, 2) void gemm_top2(
    const unsigned short* __restrict__ Abig, const unsigned short* __restrict__ Bbig,
    const float* __restrict__ wsq,
    unsigned long long* __restrict__ P, unsigned long long* __restrict__ P2) {
    __shared__ unsigned short sAB[65536];

    int t = threadIdx.x;
    int l = t & 63, w = t >> 6;
    int wm = w >> 2, wn = w & 3;
    int kc0 = blockIdx.y * 256;   // code base (C rows)
    int n0 = blockIdx.x * 256;    // point base (C cols)

    int row0 = t >> 2;
    int lsw = (((t & 3) ^ ((row0 >> 1) & 3)) << 3);
    int subsw = (((l >> 4) ^ ((l >> 1) & 3)) << 3);

#define STAGE(kt_) do {                                                        \
    int p_ = (kt_) >> 3;                                                       \
    int zo_ = (p_ == 2 ? 256 : 0) + ((kt_) & 7) * 32;                          \
    int wo_ = (p_ == 1 ? 256 : 0) + ((kt_) & 7) * 32;                          \
    int b_ = ((kt_) & 3) * 16384;                                              \
    GLOAD16(Bbig + (size_t)(kc0 + row0) * 512 + wo_ + lsw, &sAB[b_ + t * 8]);  \
    GLOAD16(Bbig + (size_t)(kc0 + row0 + 128) * 512 + wo_ + lsw, &sAB[b_ + 4096 + t * 8]); \
    GLOAD16(Abig + (size_t)(n0 + row0) * 512 + zo_ + lsw, &sAB[b_ + 8192 + t * 8]); \
    GLOAD16(Abig + (size_t)(n0 + row0 + 128) * 512 + zo_ + lsw, &sAB[b_ + 12288 + t * 8]); \
} while (0)

#define LDFRAG(bufbase, fa, fb) do {                                           \
    _Pragma("unroll")                                                          \
    for (int mf = 0; mf < 8; ++mf)                                             \
        fa[mf] = *(const bf16x8*)&sAB[(bufbase) + (wm * 128 + mf * 16 + (l & 15)) * 32 + subsw]; \
    _Pragma("unroll")                                                          \
    for (int nf = 0; nf < 4; ++nf)                                             \
        fb[nf] = *(const bf16x8*)&sAB[(bufbase) + 8192 + (wn * 64 + nf * 16 + (l & 15)) * 32 + subsw]; \
} while (0)

#define MFMACL(fa, fb) do {                                                    \
    __builtin_amdgcn_s_setprio(1);                                             \
    _Pragma("unroll")                                                          \
    for (int mf = 0; mf < 8; ++mf)                                             \
        _Pragma("unroll")                                                      \
        for (int nf = 0; nf < 4; ++nf)                                         \
            acc[mf][nf] = __builtin_amdgcn_mfma_f32_16x16x32_bf16(fa[mf], fb[nf], acc[mf][nf], 0, 0, 0); \
    __builtin_amdgcn_s_setprio(0);                                             \
} while (0)

#define WAITBAR(n_) do {                                                       \
    asm volatile("s_waitcnt vmcnt(" #n_ ")" ::: "memory");                     \
    __builtin_amdgcn_s_barrier();                                              \
    asm volatile("" ::: "memory");                                             \
} while (0)

    f32x4 acc[8][4];
#pragma unroll
    for (int mf = 0; mf < 8; ++mf) {
#pragma unroll
        for (int r = 0; r < 4; ++r) {
            float hv = -0.5f * wsq[kc0 + wm * 128 + mf * 16 + ((l >> 4) << 2) + r];
#pragma unroll
            for (int nf = 0; nf < 4; ++nf) acc[mf][nf][r] = hv;
        }
    }

    bf16x8 fa0[8], fb0[4], fa1[8], fb1[4];

    STAGE(0);
    STAGE(1);
    STAGE(2);
    WAITBAR(8);
    LDFRAG(0, fa0, fb0);

    for (int kt = 0; kt < 20; kt += 2) {
        WAITBAR(4);
        LDFRAG(((kt + 1) & 3) * 16384, fa1, fb1);
        STAGE(kt + 3);
        MFMACL(fa0, fb0);
        WAITBAR(4);
        LDFRAG(((kt + 2) & 3) * 16384, fa0, fb0);
        STAGE(kt + 4);
        MFMACL(fa1, fb1);
    }
    WAITBAR(4);
    LDFRAG(1 * 16384, fa1, fb1);
    STAGE(23);
    MFMACL(fa0, fb0);
    WAITBAR(4);
    LDFRAG(2 * 16384, fa0, fb0);
    MFMACL(fa1, fb1);
    WAITBAR(0);
    LDFRAG(3 * 16384, fa1, fb1);
    MFMACL(fa0, fb0);
    MFMACL(fa1, fb1);

    // ---- top-2 screen (s-space: dv = -acc, smaller = better) ----
    float v1[4], v2[4];
    int k1[4];
#pragma unroll
    for (int nf = 0; nf < 4; ++nf) { v1[nf] = 3.4e38f; v2[nf] = 3.4e38f; k1[nf] = 0; }
#pragma unroll
    for (int mf = 0; mf < 8; ++mf) {
#pragma unroll
        for (int r = 0; r < 4; ++r) {
            int code = kc0 + wm * 128 + mf * 16 + ((l >> 4) << 2) + r;
#pragma unroll
            for (int nf = 0; nf < 4; ++nf) {
                float dv = -acc[mf][nf][r];
                bool lt = dv < v1[nf];
                v2[nf] = fminf(v2[nf], fmaxf(v1[nf], dv));
                v1[nf] = fminf(v1[nf], dv);
                k1[nf] = lt ? code : k1[nf];
            }
        }
    }
#pragma unroll
    for (int nf = 0; nf < 4; ++nf) {
#pragma unroll
        for (int mask = 16; mask <= 32; mask <<= 1) {
            float ov1 = __shfl_xor(v1[nf], mask, 64);
            float ov2 = __shfl_xor(v2[nf], mask, 64);
            int ok1 = __shfl_xor(k1[nf], mask, 64);
            bool take = (ov1 < v1[nf]) || (ov1 == v1[nf] && ok1 < k1[nf]);
            if (take) { v2[nf] = fminf(v1[nf], ov2); v1[nf] = ov1; k1[nf] = ok1; }
            else v2[nf] = fminf(v2[nf], ov1);
        }
    }
    __syncthreads();
    float* sv1 = (float*)sAB;            // [256][2]
    float* sv2 = sv1 + 512;
    int* sk1 = (int*)(sv2 + 512);
    if ((l >> 4) == 0) {
#pragma unroll
        for (int nf = 0; nf < 4; ++nf) {
            int col = wn * 64 + nf * 16 + l;
            sv1[col * 2 + wm] = v1[nf];
            sv2[col * 2 + wm] = v2[nf];
            sk1[col * 2 + wm] = k1[nf];
        }
    }
    __syncthreads();
    if (t < 256) {
        float a1 = sv1[t * 2], b1 = sv1[t * 2 + 1];
        float a2 = sv2[t * 2], b2 = sv2[t * 2 + 1];
        int ak = sk1[t * 2], bk = sk1[t * 2 + 1];
        bool tb = (b1 < a1) || (b1 == a1 && bk < ak);
        float w1 = tb ? b1 : a1;
        int wk = tb ? bk : ak;
        float w2 = tb ? fminf(b2, a1) : fminf(a2, b1);
        int n = n0 + t;
        unsigned long long x = ((unsigned long long)mono(w1) << 32) | (unsigned)wk;
        unsigned long long old = atomicMin(&P[n], x);
        atomicMin(&P2[n], old > x ? old : x);
        atomicMin(&P2[n], ((unsigned long long)mono(w2) << 32) | 0xFFFFFFFFull);
    }
#undef STAGE
#undef LDFRAG
#undef MFMACL
#undef WAITBAR
}

// exact fp32 rescore of ambiguous rows (flag recomputed from P/P2), wave-coop.
// grid (64, 32): block (bx, c) handles rows n ≡ bx (mod 64), codes c*256..+255.
__global__ __launch_bounds__(256) void rescore_par(
    const float* __restrict__ z, const float* __restrict__ cb,
    const float* __restrict__ nrm, const float* __restrict__ wsq,
    const unsigned long long* __restrict__ P, const unsigned long long* __restrict__ P2,
    unsigned long long* __restrict__ R) {
    __shared__ float sz[256];
    __shared__ unsigned char fl[128];
    int t = threadIdx.x;
    int lane = t & 63, wv = t >> 6;
    if (t < 128) {
        int n = blockIdx.x + t * 64;
        float s1 = invmono((unsigned)(P[n] >> 32));
        float s2 = invmono((unsigned)(P2[n] >> 32));
        fl[t] = (s2 - s1 < MARGIN_S) ? 1 : 0;
    }
    __syncthreads();
    for (int ii = 0; ii < 128; ++ii) {
        if (!fl[ii]) continue;
        int n = blockIdx.x + ii * 64;
        int b = n >> 10, hw = n & 1023;
        __syncthreads();
        sz[t] = z[(b * DD + t) * 1024 + hw];
        __syncthreads();
        float4 zr = ((const float4*)sz)[lane];
        double zqd = (double)zr.x * zr.x + (double)zr.y * zr.y
                   + (double)zr.z * zr.z + (double)zr.w * zr.w;
#pragma unroll
        for (int off = 32; off; off >>= 1) zqd += __shfl_xor(zqd, off, 64);
        float zq = (float)zqd;
        unsigned long long best = 0xFFFFFFFFFFFFFFFFull;
        int kbase = blockIdx.y * 256 + wv * 64;
        for (int j = 0; j < 64; ++j) {
            int k = kbase + j;
            float4 cc = *(const float4*)&cb[(size_t)k * DD + lane * 4];
            float p = (zr.x * cc.x + zr.y * cc.y) + (zr.z * cc.z + zr.w * cc.w);
#pragma unroll
            for (int off = 32; off; off >>= 1) p += __shfl_xor(p, off, 64);
            float dot = p / nrm[k];
            float dv = (zq + wsq[k]) - 2.0f * dot;
            unsigned long long pk = ((unsigned long long)mono(dv) << 32) | (unsigned)k;
            best = best < pk ? best : pk;
        }
        if (lane == 0) atomicMin(&R[n], best);
    }
}

// z_q gather + idx out + histogram + loss partials + fused finalize (last block)
__global__ __launch_bounds__(256) void gather_fin(
    const float* __restrict__ z, const float* __restrict__ cb,
    const float* __restrict__ nrm,
    const unsigned long long* __restrict__ P, const unsigned long long* __restrict__ P2,
    const unsigned long long* __restrict__ R,
    float* __restrict__ out, double* __restrict__ lossp, int* __restrict__ hist,
    unsigned int* __restrict__ done) {
    __shared__ double lred[4];
    __shared__ int amLast;
    __shared__ double lsum;
    int t = threadIdx.x;
    int lane = t & 63, wid = t >> 6;
    int base = (blockIdx.x * 256 + t) * 16;
    double s = 0.0;
#pragma unroll
    for (int q = 0; q < 4; ++q) {
        int e = base + q * 4;
        int b = e >> 18, d = (e >> 10) & 255, hw = e & 1023;
        int n = (b << 10) + hw;
        float4 zv = *(const float4*)&z[e];
        float o[4];
        int ks[4];
#pragma unroll
        for (int j = 0; j < 4; ++j) {
            unsigned long long p = P[n + j];
            float s1 = invmono((unsigned)(p >> 32));
            float s2 = invmono((unsigned)(P2[n + j] >> 32));
            unsigned long long wnr = (s2 - s1 < MARGIN_S) ? R[n + j] : p;
            ks[j] = (int)(wnr & 0xFFFFFFFFull);
            o[j] = cb[ks[j] * DD + d] / nrm[ks[j]];
        }
        *(float4*)&out[e] = make_float4(o[0], o[1], o[2], o[3]);
        if (d == 0) {
#pragma unroll
            for (int j = 0; j < 4; ++j) {
                out[ZQ_ELEMS + n + j] = (float)ks[j];
                atomicAdd(&hist[ks[j]], 1);
            }
        }
        float d0 = o[0] - zv.x, d1 = o[1] - zv.y, d2 = o[2] - zv.z, d3 = o[3] - zv.w;
        s += (double)(d0 * d0) + (double)(d1 * d1) + (double)(d2 * d2) + (double)(d3 * d3);
    }
    s = waveReduceD(s);
    if (lane == 0) lred[wid] = s;
    __syncthreads();
    if (t == 0) lossp[blockIdx.x] = lred[0] + lred[1] + lred[2] + lred[3];
    __threadfence();                 // all threads: flush hist atomics + lossp
    __syncthreads();
    if (t == 0) amLast = (atomicAdd(done, 1u) == (unsigned)(gridDim.x - 1)) ? 1 : 0;
    __syncthreads();
    if (amLast) {
        __threadfence();             // acquire
        double ls = lossp[t] + lossp[t + 256];
        ls = waveReduceD(ls);
        if (lane == 0) lred[wid] = ls;
        __syncthreads();
        if (t == 0) lsum = lred[0] + lred[1] + lred[2] + lred[3];
        __syncthreads();
        double ps = 0.0;
        for (int i = t; i < KC; i += 256) {
            float p = (float)hist[i] * (1.0f / 8192.0f);
            float lg = logf(p + 1e-10f);
            ps += (double)(p * lg);
        }
        ps = waveReduceD(ps);
        if (lane == 0) lred[wid] = ps;
        __syncthreads();
        if (t == 0) {
            double tot = lred[0] + lred[1] + lred[2] + lred[3];
            float m = (float)(lsum / (double)ZQ_ELEMS);
            out[ZQ_ELEMS + NP] = m + 0.25f * m;
            out[ZQ_ELEMS + NP + 1] = expf(-(float)tot);
        }
    }
}

extern "C" void kernel_launch(void* const* d_in, const int* in_sizes, int n_in,
                              void* d_out, int out_size, void* d_ws, size_t ws_size,
                              hipStream_t stream) {
    const float* z = (const float*)d_in[0];
    const float* cb = (const float*)d_in[1];
    float* out = (float*)d_out;
    char* ws = (char*)d_ws;

    unsigned short* Abig = (unsigned short*)(ws + OFF_ABIG);
    unsigned short* Bbig = (unsigned short*)(ws + OFF_BBIG);
    float* nrm = (float*)(ws + OFF_NRM);
    float* wsq = (float*)(ws + OFF_WSQ);
    unsigned long long* P = (unsigned long long*)(ws + OFF_P);
    unsigned long long* P2 = (unsigned long long*)(ws + OFF_P2);
    unsigned long long* R = (unsigned long long*)(ws + OFF_R);
    double* lossp = (double*)(ws + OFF_LOSSP);
    int* hist = (int*)(ws + OFF_HIST);
    unsigned int* done = (unsigned int*)(ws + OFF_DONE);

    prep<<<2560, 256, 0, stream>>>(cb, z, Bbig, Abig, nrm, wsq, hist, P, P2, R, done);
    gemm_top2<<<dim3(32, 32), 512, 0, stream>>>(Abig, Bbig, wsq, P, P2);
    rescore_par<<<dim3(64, 32), 256, 0, stream>>>(z, cb, nrm, wsq, P, P2, R);
    gather_fin<<<512, 256, 0, stream>>>(z, cb, nrm, P, P2, R, out, lossp, hist, done);
}

// Round 13
// 186.348 us; speedup vs baseline: 1.5762x; 1.5762x over previous
//
#include <hip/hip_runtime.h>
#include <hip/hip_bf16.h>
#include <math.h>

// VectorQuantizer: z [8,256,32,32] f32, codebook [8192,256] f32
// outputs (flat f32): z_q [2097152] NCHW, idx [8192] (as float), loss, perplexity
#define KC 8192
#define DD 256
#define NP 8192
#define ZQ_ELEMS 2097152
#define MARGIN_S 2.5e-4f   // s-space (== 5e-4 in d-space, validated rounds 4-11)
#define NPART 8            // code-group partials (gemm grid.y)

// ws layout (bytes)
#define OFF_ABIG 0u           // bf16 [8192][512]  (Zh | Zl)  points
#define OFF_BBIG 8388608u     // bf16 [8192][512]  (Wh | Wl)  codes
#define OFF_NRM  16777216u    // f32 [8192]
#define OFF_WSQ  16809984u    // f32 [8192]
#define OFF_PV1  16875520u    // f32 [8192][8]  (transposed partials)
#define OFF_PV2  17924096u    // f32 [8192][8]
#define OFF_PK1  18972672u    // i32 [8192][8]
#define OFF_LOSSP 20021248u   // f64 [512]
#define OFF_HIST 20090880u    // i32 [8192]
#define OFF_PACK 20123648u    // u64 [8192]
#define OFF_LIST 20189184u    // i32 [8192]
#define OFF_NFLG 20221952u    // i32 [1]

typedef __attribute__((ext_vector_type(8))) short bf16x8;
typedef __attribute__((ext_vector_type(4))) float f32x4;
typedef __attribute__((address_space(3))) void as3_void;
typedef const __attribute__((address_space(1))) void as1_cvoid;

#define GLOAD16(g, l) __builtin_amdgcn_global_load_lds((as1_cvoid*)(g), (as3_void*)(l), 16, 0, 0)

__device__ inline double waveReduceD(double v) {
#pragma unroll
    for (int off = 32; off; off >>= 1) v += __shfl_down(v, off, 64);
    return v;
}

static __device__ inline unsigned short f2bf(float f) {
    __hip_bfloat16 h = __float2bfloat16(f);  // RNE
    return *(unsigned short*)&h;
}
static __device__ inline float bf2f(unsigned short u) {
    unsigned v = ((unsigned)u) << 16;
    float f;
    __builtin_memcpy(&f, &v, 4);
    return f;
}

// fused prep:
//   blocks 0..2047: 4 codebook rows each (wave-per-row: normalize + split +
//                   wsq/nrm); blocks 0..31 zero hist; block 32 zeroes nflag
//   blocks 2048..2559: z tile-transpose (64d x 64hw, LDS-staged) + hi/lo split
__global__ __launch_bounds__(256) void prep(
    const float* __restrict__ cb, const float* __restrict__ z,
    unsigned short* __restrict__ Bbig, unsigned short* __restrict__ Abig,
    float* __restrict__ nrm, float* __restrict__ wsq,
    int* __restrict__ hist, int* __restrict__ nflag) {
    int bid = blockIdx.x, t = threadIdx.x;
    int lane = t & 63, wid = t >> 6;
    if (bid < 2048) {
        if (bid < 32) hist[bid * 256 + t] = 0;
        if (bid == 32 && t == 0) *nflag = 0;
        int k = bid * 4 + wid;
        float4 c4 = *(const float4*)&cb[(size_t)k * DD + lane * 4];
        double s = (double)c4.x * c4.x + (double)c4.y * c4.y
                 + (double)c4.z * c4.z + (double)c4.w * c4.w;
#pragma unroll
        for (int off = 32; off; off >>= 1) s += __shfl_xor(s, off, 64);
        float mh = fmaxf(sqrtf((float)s), 1e-12f);
        if (lane == 0) {
            nrm[k] = mh;
            wsq[k] = (float)(s / ((double)mh * (double)mh));
        }
        float wv[4] = {c4.x / mh, c4.y / mh, c4.z / mh, c4.w / mh};
        unsigned short hi[4], lo[4];
#pragma unroll
        for (int j = 0; j < 4; ++j) {
            hi[j] = f2bf(wv[j]);
            lo[j] = f2bf(wv[j] - bf2f(hi[j]));
        }
        *(ushort4*)&Bbig[(size_t)k * 512 + lane * 4] = make_ushort4(hi[0], hi[1], hi[2], hi[3]);
        *(ushort4*)&Bbig[(size_t)k * 512 + 256 + lane * 4] = make_ushort4(lo[0], lo[1], lo[2], lo[3]);
    } else {
        __shared__ float tile[64][65];
        int zb = bid - 2048;               // 0..511
        int b = zb >> 6, ht = (zb >> 2) & 15, dt = zb & 3;
        int hw0 = ht * 64, d0 = dt * 64;
#pragma unroll
        for (int i = 0; i < 16; ++i) {
            int dl = wid * 16 + i;
            tile[dl][lane] = z[(size_t)(b * DD + d0 + dl) * 1024 + hw0 + lane];
        }
        __syncthreads();
        // point row n = b*1024+hw0+nl needs z(d=d0+lane, hw=hw0+nl) == tile[lane][nl]
#pragma unroll
        for (int i = 0; i < 16; ++i) {
            int nl = wid * 16 + i;
            float v = tile[lane][nl];
            unsigned short hi = f2bf(v);
            unsigned short lo = f2bf(v - bf2f(hi));
            size_t base = (size_t)(b * 1024 + hw0 + nl) * 512 + d0 + lane;
            Abig[base] = hi;
            Abig[base + 256] = lo;
        }
    }
}

// Deep-pipelined MFMA GEMM + top-2 screen.
// R11 cadence (quad-buffer, depth-3 staging, counted vmcnt(8), reg fragment
// pipeline, 1 barrier/tile) extended to a single 96-tile loop: each block
// sweeps 4 code-tiles (1024 codes) with NO pipeline drain at boundaries —
// per-ct top-2 extracted into persistent registers, acc re-inited from wsq.
// grid (32, 8) = 256 blocks = 1/CU. acc init = -wsq/2 => dv = -acc.
__global__ __launch_bounds__(512, 2) void gemm_top2(
    const unsigned short* __restrict__ Abig, const unsigned short* __restrict__ Bbig,
    const float* __restrict__ wsq,
    float* __restrict__ pv1, float* __restrict__ pv2, int* __restrict__ pk1) {
    __shared__ unsigned short sAB[65536];  // 4 bufs x [W 256x32 | Z 256x32]

    int t = threadIdx.x;
    int l = t & 63, w = t >> 6;
    int wm = w >> 2, wn = w & 3;
    int kc0 = blockIdx.y * 1024;  // this block's 1024-code range
    int n0 = blockIdx.x * 256;    // point base (C cols)

    int row0 = t >> 2;
    int lsw = (((t & 3) ^ ((row0 >> 1) & 3)) << 3);
    int subsw = (((l >> 4) ^ ((l >> 1) & 3)) << 3);

#define STAGE(g_) do {                                                         \
    int ct_ = (g_) / 24;                                                       \
    int kt_ = (g_) % 24;                                                       \
    int p_ = kt_ >> 3;                                                         \
    int zo_ = (p_ == 2 ? 256 : 0) + (kt_ & 7) * 32;                            \
    int wo_ = (p_ == 1 ? 256 : 0) + (kt_ & 7) * 32;                            \
    int b_ = ((g_) & 3) * 16384;                                               \
    int kc_ = kc0 + ct_ * 256;                                                 \
    GLOAD16(Bbig + (size_t)(kc_ + row0) * 512 + wo_ + lsw, &sAB[b_ + t * 8]);  \
    GLOAD16(Bbig + (size_t)(kc_ + row0 + 128) * 512 + wo_ + lsw, &sAB[b_ + 4096 + t * 8]); \
    GLOAD16(Abig + (size_t)(n0 + row0) * 512 + zo_ + lsw, &sAB[b_ + 8192 + t * 8]); \
    GLOAD16(Abig + (size_t)(n0 + row0 + 128) * 512 + zo_ + lsw, &sAB[b_ + 12288 + t * 8]); \
} while (0)

#define LDFRAG(bufbase, fa, fb) do {                                           \
    _Pragma("unroll")                                                          \
    for (int mf = 0; mf < 8; ++mf)                                             \
        fa[mf] = *(const bf16x8*)&sAB[(bufbase) + (wm * 128 + mf * 16 + (l & 15)) * 32 + subsw]; \
    _Pragma("unroll")                                                          \
    for (int nf = 0; nf < 4; ++nf)                                             \
        fb[nf] = *(const bf16x8*)&sAB[(bufbase) + 8192 + (wn * 64 + nf * 16 + (l & 15)) * 32 + subsw]; \
} while (0)

#define MFMACL(fa, fb) do {                                                    \
    __builtin_amdgcn_s_setprio(1);                                             \
    _Pragma("unroll")                                                          \
    for (int mf = 0; mf < 8; ++mf)                                             \
        _Pragma("unroll")                                                      \
        for (int nf = 0; nf < 4; ++nf)                                         \
            acc[mf][nf] = __builtin_amdgcn_mfma_f32_16x16x32_bf16(fa[mf], fb[nf], acc[mf][nf], 0, 0, 0); \
    __builtin_amdgcn_s_setprio(0);                                             \
} while (0)

#define WAITBAR(n_) do {                                                       \
    asm volatile("s_waitcnt vmcnt(" #n_ ")" ::: "memory");                     \
    __builtin_amdgcn_s_barrier();                                              \
    asm volatile("" ::: "memory");                                             \
} while (0)

#define RESETACC(ct_) do {                                                     \
    _Pragma("unroll")                                                          \
    for (int mf = 0; mf < 8; ++mf) {                                           \
        _Pragma("unroll")                                                      \
        for (int r = 0; r < 4; ++r) {                                          \
            float hv = -0.5f * wsq[kc0 + (ct_) * 256 + wm * 128 + mf * 16 + ((l >> 4) << 2) + r]; \
            _Pragma("unroll")                                                  \
            for (int nf = 0; nf < 4; ++nf) acc[mf][nf][r] = hv;                \
        }                                                                      \
    }                                                                          \
} while (0)

#define EXTRACT(ct_) do {                                                      \
    _Pragma("unroll")                                                          \
    for (int mf = 0; mf < 8; ++mf) {                                           \
        _Pragma("unroll")                                                      \
        for (int r = 0; r < 4; ++r) {                                          \
            int code = kc0 + (ct_) * 256 + wm * 128 + mf * 16 + ((l >> 4) << 2) + r; \
            _Pragma("unroll")                                                  \
            for (int nf = 0; nf < 4; ++nf) {                                   \
                float dv = -acc[mf][nf][r];                                    \
                bool lt = dv < v1[nf];                                         \
                v2[nf] = fminf(v2[nf], fmaxf(v1[nf], dv));                     \
                v1[nf] = fminf(v1[nf], dv);                                    \
                k1[nf] = lt ? code : k1[nf];                                   \
            }                                                                  \
        }                                                                      \
    }                                                                          \
} while (0)

    float v1[4], v2[4];
    int k1[4];
#pragma unroll
    for (int nf = 0; nf < 4; ++nf) { v1[nf] = 3.4e38f; v2[nf] = 3.4e38f; k1[nf] = 0; }

    f32x4 acc[8][4];
    RESETACC(0);

    bf16x8 fa0[8], fb0[4], fa1[8], fb1[4];

    // prologue: stage tiles 0,1,2; tile 0 resident (8 loads stay in flight)
    STAGE(0);
    STAGE(1);
    STAGE(2);
    WAITBAR(8);
    LDFRAG(0, fa0, fb0);

    // 96-tile loop (tiles 0..93 here; 94,95 in tail). Boundary extracts at
    // tile 23/47/71 (ct 0/1/2); ct 3 extracted in tail.
    for (int g = 0; g < 94; g += 2) {
        WAITBAR(4);                               // tile g+1 resident
        LDFRAG(((g + 1) & 3) * 16384, fa1, fb1);
        STAGE(g + 3);                             // g <= 92 -> g+3 <= 95
        MFMACL(fa0, fb0);                         // tile g
        WAITBAR(4);                               // tile g+2 resident
        LDFRAG(((g + 2) & 3) * 16384, fa0, fb0);
        if (g < 92) STAGE(g + 4);
        MFMACL(fa1, fb1);                         // tile g+1
        if (((g + 1) % 24) == 23) {
            int ct = (g + 1) / 24;
            EXTRACT(ct);
            RESETACC(ct + 1);                     // ct < 3 always here
        }
    }
    // tail: tiles 94, 95
    WAITBAR(0);                                   // tile 95 resident
    LDFRAG(3 * 16384, fa1, fb1);
    MFMACL(fa0, fb0);                             // tile 94
    MFMACL(fa1, fb1);                             // tile 95
    EXTRACT(3);

    // merge across the 4 row-groups (lanes l, l^16, l^32, l^48 share cols)
#pragma unroll
    for (int nf = 0; nf < 4; ++nf) {
#pragma unroll
        for (int mask = 16; mask <= 32; mask <<= 1) {
            float ov1 = __shfl_xor(v1[nf], mask, 64);
            float ov2 = __shfl_xor(v2[nf], mask, 64);
            int ok1 = __shfl_xor(k1[nf], mask, 64);
            bool take = (ov1 < v1[nf]) || (ov1 == v1[nf] && ok1 < k1[nf]);
            if (take) { v2[nf] = fminf(v1[nf], ov2); v1[nf] = ov1; k1[nf] = ok1; }
            else v2[nf] = fminf(v2[nf], ov1);
        }
    }
    __syncthreads();  // pipeline fully done; reuse LDS for cross-wave merge
    float* sv1 = (float*)sAB;            // [256][2]
    float* sv2 = sv1 + 512;
    int* sk1 = (int*)(sv2 + 512);
    if ((l >> 4) == 0) {
#pragma unroll
        for (int nf = 0; nf < 4; ++nf) {
            int col = wn * 64 + nf * 16 + l;
            sv1[col * 2 + wm] = v1[nf];
            sv2[col * 2 + wm] = v2[nf];
            sk1[col * 2 + wm] = k1[nf];
        }
    }
    __syncthreads();
    if (t < 256) {
        float a1 = sv1[t * 2], b1 = sv1[t * 2 + 1];
        float a2 = sv2[t * 2], b2 = sv2[t * 2 + 1];
        int ak = sk1[t * 2], bk = sk1[t * 2 + 1];
        bool tb = (b1 < a1) || (b1 == a1 && bk < ak);
        float w1 = tb ? b1 : a1;
        int wk = tb ? bk : ak;
        float w2 = tb ? fminf(b2, a1) : fminf(a2, b1);
        pv1[(size_t)(n0 + t) * NPART + blockIdx.y] = w1;
        pv2[(size_t)(n0 + t) * NPART + blockIdx.y] = w2;
        pk1[(size_t)(n0 + t) * NPART + blockIdx.y] = wk;
    }
#undef STAGE
#undef LDFRAG
#undef MFMACL
#undef WAITBAR
#undef RESETACC
#undef EXTRACT
}

// merge 8 partials per point (contiguous); packed holds winner k (or ~0
// sentinel for flagged rows, which rescore_par atomicMin-fills exactly)
__global__ __launch_bounds__(256) void merge_top2(
    const float* __restrict__ pv1, const float* __restrict__ pv2,
    const int* __restrict__ pk1, int* __restrict__ list, int* __restrict__ nflag,
    unsigned long long* __restrict__ packed) {
    int n = blockIdx.x * 256 + threadIdx.x;
    float gv1 = 3.4e38f, gv2 = 3.4e38f;
    int gk1 = 0;
#pragma unroll
    for (int ct = 0; ct < NPART; ++ct) {
        float v1 = pv1[(size_t)n * NPART + ct];
        if (v1 < gv1) {
            gv2 = fminf(gv1, pv2[(size_t)n * NPART + ct]);
            gv1 = v1;
            gk1 = pk1[(size_t)n * NPART + ct];
        } else {
            gv2 = fminf(gv2, v1);
        }
    }
    int f = (gv2 - gv1 < MARGIN_S) ? 1 : 0;
    packed[n] = f ? 0xFFFFFFFFFFFFFFFFull : (unsigned long long)(unsigned)gk1;
    if (f) {
        int pos = atomicAdd(nflag, 1);
        list[pos] = n;
    }
}

// exact fp32 rescore of flagged rows, wave-cooperative (lanes along D).
__global__ __launch_bounds__(256) void rescore_par(
    const float* __restrict__ z, const float* __restrict__ cb,
    const float* __restrict__ nrm, const float* __restrict__ wsq,
    const int* __restrict__ list, const int* __restrict__ nflag,
    unsigned long long* __restrict__ packed) {
    __shared__ float sz[256];
    int nf = *nflag;
    int t = threadIdx.x;
    int lane = t & 63, wv = t >> 6;
    for (int ii = blockIdx.x; ii < nf; ii += 64) {
        int n = list[ii];
        int b = n >> 10, hw = n & 1023;
        __syncthreads();
        sz[t] = z[(b * DD + t) * 1024 + hw];
        __syncthreads();
        float4 zr = ((const float4*)sz)[lane];
        double zqd = (double)zr.x * zr.x + (double)zr.y * zr.y
                   + (double)zr.z * zr.z + (double)zr.w * zr.w;
#pragma unroll
        for (int off = 32; off; off >>= 1) zqd += __shfl_xor(zqd, off, 64);
        float zq = (float)zqd;
        unsigned long long best = 0xFFFFFFFFFFFFFFFFull;
        int kbase = blockIdx.y * 256 + wv * 64;
        for (int j = 0; j < 64; ++j) {
            int k = kbase + j;
            float4 cc = *(const float4*)&cb[(size_t)k * DD + lane * 4];
            float p = (zr.x * cc.x + zr.y * cc.y) + (zr.z * cc.z + zr.w * cc.w);
#pragma unroll
            for (int off = 32; off; off >>= 1) p += __shfl_xor(p, off, 64);
            float dot = p / nrm[k];
            float dv = (zq + wsq[k]) - 2.0f * dot;
            unsigned bits = __float_as_uint(dv);
            bits = (bits & 0x80000000u) ? ~bits : (bits | 0x80000000u);
            unsigned long long pk = ((unsigned long long)bits << 32) | (unsigned)k;
            best = best < pk ? best : pk;
        }
        if (lane == 0) atomicMin(packed + n, best);
    }
}

// z_q gather (w = cb/nrm, identical rounding to prep) + loss partials;
// the d==0 slice also emits idx output + histogram.
__global__ __launch_bounds__(256) void gather_loss(
    const float* __restrict__ z, const float* __restrict__ cb,
    const float* __restrict__ nrm, const unsigned long long* __restrict__ packed,
    float* __restrict__ out, double* __restrict__ lossp, int* __restrict__ hist) {
    __shared__ double lred[4];
    int t = threadIdx.x;
    int base = (blockIdx.x * 256 + t) * 16;
    double s = 0.0;
#pragma unroll
    for (int q = 0; q < 4; ++q) {
        int e = base + q * 4;
        int b = e >> 18, d = (e >> 10) & 255, hw = e & 1023;
        int n = (b << 10) + hw;
        float4 zv = *(const float4*)&z[e];
        float o[4];
        int ks[4];
#pragma unroll
        for (int j = 0; j < 4; ++j) {
            ks[j] = (int)(packed[n + j] & 0xFFFFFFFFull);
            o[j] = cb[ks[j] * DD + d] / nrm[ks[j]];
        }
        *(float4*)&out[e] = make_float4(o[0], o[1], o[2], o[3]);
        if (d == 0) {
#pragma unroll
            for (int j = 0; j < 4; ++j) {
                out[ZQ_ELEMS + n + j] = (float)ks[j];
                atomicAdd(&hist[ks[j]], 1);
            }
        }
        float d0 = o[0] - zv.x, d1 = o[1] - zv.y, d2 = o[2] - zv.z, d3 = o[3] - zv.w;
        s += (double)(d0 * d0) + (double)(d1 * d1) + (double)(d2 * d2) + (double)(d3 * d3);
    }
    s = waveReduceD(s);
    int lane = t & 63, wid = t >> 6;
    if (lane == 0) lred[wid] = s;
    __syncthreads();
    if (t == 0) lossp[blockIdx.x] = lred[0] + lred[1] + lred[2] + lred[3];
}

// single block: loss from 512 partials + perplexity from histogram
__global__ __launch_bounds__(256) void finalize_kernel(
    const int* __restrict__ hist, const double* __restrict__ lossp,
    float* __restrict__ out) {
    __shared__ double lred[4];
    __shared__ double lsum;
    int t = threadIdx.x;
    int lane = t & 63, wid = t >> 6;
    double ls = lossp[t] + lossp[t + 256];
    ls = waveReduceD(ls);
    if (lane == 0) lred[wid] = ls;
    __syncthreads();
    if (t == 0) lsum = lred[0] + lred[1] + lred[2] + lred[3];
    __syncthreads();
    double s = 0.0;
    for (int i = t; i < KC; i += 256) {
        float p = (float)hist[i] * (1.0f / 8192.0f);
        float lg = logf(p + 1e-10f);
        s += (double)(p * lg);
    }
    s = waveReduceD(s);
    if (lane == 0) lred[wid] = s;
    __syncthreads();
    if (t == 0) {
        double tot = lred[0] + lred[1] + lred[2] + lred[3];
        float m = (float)(lsum / (double)ZQ_ELEMS);
        out[ZQ_ELEMS + NP] = m + 0.25f * m;
        out[ZQ_ELEMS + NP + 1] = expf(-(float)tot);
    }
}

extern "C" void kernel_launch(void* const* d_in, const int* in_sizes, int n_in,
                              void* d_out, int out_size, void* d_ws, size_t ws_size,
                              hipStream_t stream) {
    const float* z = (const float*)d_in[0];
    const float* cb = (const float*)d_in[1];
    float* out = (float*)d_out;
    char* ws = (char*)d_ws;

    unsigned short* Abig = (unsigned short*)(ws + OFF_ABIG);
    unsigned short* Bbig = (unsigned short*)(ws + OFF_BBIG);
    float* nrm = (float*)(ws + OFF_NRM);
    float* wsq = (float*)(ws + OFF_WSQ);
    float* pv1 = (float*)(ws + OFF_PV1);
    float* pv2 = (float*)(ws + OFF_PV2);
    int* pk1 = (int*)(ws + OFF_PK1);
    int* hist = (int*)(ws + OFF_HIST);
    double* lossp = (double*)(ws + OFF_LOSSP);
    unsigned long long* packed = (unsigned long long*)(ws + OFF_PACK);
    int* list = (int*)(ws + OFF_LIST);
    int* nflag = (int*)(ws + OFF_NFLG);

    prep<<<2560, 256, 0, stream>>>(cb, z, Bbig, Abig, nrm, wsq, hist, nflag);
    gemm_top2<<<dim3(32, NPART), 512, 0, stream>>>(Abig, Bbig, wsq, pv1, pv2, pk1);
    merge_top2<<<NP / 256, 256, 0, stream>>>(pv1, pv2, pk1, list, nflag, packed);
    rescore_par<<<dim3(64, 32), 256, 0, stream>>>(z, cb, nrm, wsq, list, nflag, packed);
    gather_loss<<<ZQ_ELEMS / (256 * 16), 256, 0, stream>>>(z, cb, nrm, packed, out, lossp, hist);
    finalize_kernel<<<1, 256, 0, stream>>>(hist, lossp, out);
}